// Round 7
// baseline (278.647 us; speedup 1.0000x reference)
//
#include <hip/hip_runtime.h>
#include <cmath>

#define D 128
#define NCLS 40

typedef __bf16 bfrag __attribute__((ext_vector_type(8)));
typedef __bf16 bf2 __attribute__((ext_vector_type(2)));
typedef float ffrag __attribute__((ext_vector_type(4)));
typedef unsigned int u32;

struct __align__(8) Edge { int s; float w; };

// ---------------- weights -> bf16, transposed [n][k] ----------------
__global__ __launch_bounds__(256) void cvt_weights(const float* __restrict__ W1, const float* __restrict__ W2,
                                                   const float* __restrict__ Wl, __bf16* __restrict__ Wt1,
                                                   __bf16* __restrict__ Wt2, __bf16* __restrict__ Wlt) {
  int i = blockIdx.x * 256 + threadIdx.x;
  if (i < 16384) {
    int n = i >> 7, k = i & 127;
    Wt1[i] = (__bf16)W1[k * D + n];
  } else if (i < 32768) {
    int j = i - 16384;
    int n = j >> 7, k = j & 127;
    Wt2[j] = (__bf16)W2[k * D + n];
  } else if (i < 32768 + 48 * D) {
    int j = i - 32768;
    int n = j >> 7, k = j & 127;
    Wlt[j] = (n < NCLS) ? (__bf16)Wl[k * NCLS + n] : (__bf16)0.0f;
  }
}

// ---------------- degree ----------------
__global__ __launch_bounds__(256) void deg_count_int(const int* __restrict__ dst, int* __restrict__ deg, int E) {
  int e = blockIdx.x * 256 + threadIdx.x;
  if (e < E) atomicAdd(&deg[dst[e]], 1);
}

// ---------------- hierarchical scan (3 kernels), dinv fused into pass 1 ----------------
__device__ inline int wave_incl_scan(int x, int lane) {
#pragma unroll
  for (int off = 1; off < 64; off <<= 1) {
    int y = __shfl_up(x, off, 64);
    if (lane >= off) x += y;
  }
  return x;
}

__global__ __launch_bounds__(256) void scan_block(const int* __restrict__ deg, float* __restrict__ dinv,
                                                  int* __restrict__ local, int* __restrict__ bsum, int n) {
  int i = blockIdx.x * 256 + threadIdx.x;
  int lane = threadIdx.x & 63, wid = threadIdx.x >> 6;
  int v = (i < n) ? deg[i] : 0;
  if (i < n) dinv[i] = rsqrtf((float)v + 1.0f);  // +1 = self-loop
  int x = wave_incl_scan(v, lane);
  __shared__ int ws4[4];
  if (lane == 63) ws4[wid] = x;
  __syncthreads();
  int wb = 0;
#pragma unroll
  for (int j = 0; j < 4; ++j) wb += (j < wid) ? ws4[j] : 0;
  if (i < n) local[i] = wb + x - v;
  if (threadIdx.x == 255) bsum[blockIdx.x] = wb + x;
}

__global__ __launch_bounds__(256) void scan_bsum(int* __restrict__ bsum, int nb) {
  int i = threadIdx.x;
  int lane = threadIdx.x & 63, wid = threadIdx.x >> 6;
  int v = (i < nb) ? bsum[i] : 0;
  int x = wave_incl_scan(v, lane);
  __shared__ int ws4[4];
  if (lane == 63) ws4[wid] = x;
  __syncthreads();
  int wb = 0;
#pragma unroll
  for (int j = 0; j < 4; ++j) wb += (j < wid) ? ws4[j] : 0;
  if (i < nb) bsum[i] = wb + x - v;
}

__global__ __launch_bounds__(256) void scan_add(int* __restrict__ rowptr, int* __restrict__ cursor,
                                                const int* __restrict__ bsum, int n, int E) {
  int i = blockIdx.x * 256 + threadIdx.x;
  if (i < n) {
    int r = rowptr[i] + bsum[blockIdx.x];
    rowptr[i] = r;
    cursor[i] = r;
  }
  if (i == 0) rowptr[n] = E;
}

// ---------------- CSR fill ----------------
__global__ __launch_bounds__(256) void fill_csr(const int* __restrict__ src, const int* __restrict__ dst,
                                                const float* __restrict__ dinv, int* __restrict__ cursor,
                                                Edge* __restrict__ csr, int E) {
  int e = blockIdx.x * 256 + threadIdx.x;
  if (e < E) {
    int s = src[e], d = dst[e];
    int pos = atomicAdd(&cursor[d], 1);
    Edge ed; ed.s = s; ed.w = dinv[s] * dinv[d];
    csr[pos] = ed;
  }
}

// ---------------- fused propagate (bf16 in/out, fp32 accumulate) ----------------
__global__ __launch_bounds__(256) void gather_bf16(const __bf16* __restrict__ t, const int* __restrict__ row_ptr,
                                                   const Edge* __restrict__ csr, const float* __restrict__ dinv,
                                                   const float* __restrict__ bias, __bf16* __restrict__ out, int N) {
  int node = blockIdx.x * 4 + (threadIdx.x >> 6);
  if (node >= N) return;
  int lane = threadIdx.x & 63;
  float dv = dinv[node];
  bf2 tv = *(const bf2*)(t + (size_t)node * D + lane * 2);
  float ax = dv * dv * (float)tv[0];
  float ay = dv * dv * (float)tv[1];
  int e = __builtin_amdgcn_readfirstlane(row_ptr[node]);
  int end = __builtin_amdgcn_readfirstlane(row_ptr[node + 1]);
  for (; e + 4 <= end; e += 4) {
    Edge e0 = csr[e], e1 = csr[e + 1], e2 = csr[e + 2], e3 = csr[e + 3];
    bf2 r0 = *(const bf2*)(t + (size_t)e0.s * D + lane * 2);
    bf2 r1 = *(const bf2*)(t + (size_t)e1.s * D + lane * 2);
    bf2 r2 = *(const bf2*)(t + (size_t)e2.s * D + lane * 2);
    bf2 r3 = *(const bf2*)(t + (size_t)e3.s * D + lane * 2);
    ax += e0.w * (float)r0[0]; ay += e0.w * (float)r0[1];
    ax += e1.w * (float)r1[0]; ay += e1.w * (float)r1[1];
    ax += e2.w * (float)r2[0]; ay += e2.w * (float)r2[1];
    ax += e3.w * (float)r3[0]; ay += e3.w * (float)r3[1];
  }
  for (; e < end; ++e) {
    Edge ed = csr[e];
    bf2 r = *(const bf2*)(t + (size_t)ed.s * D + lane * 2);
    ax += ed.w * (float)r[0]; ay += ed.w * (float)r[1];
  }
  float2 bv = *(const float2*)(bias + lane * 2);
  bf2 o;
  o[0] = (__bf16)tanhf(ax + bv.x);
  o[1] = (__bf16)tanhf(ay + bv.y);
  __builtin_nontemporal_store(*(u32*)&o, (u32*)(out + (size_t)node * D + lane * 2));
}

// ---------------- gather2 + head fused, wave-local (no barrier, broadcast-only LDS) ----------------
__global__ __launch_bounds__(256) void gather_head(const __bf16* __restrict__ t, const int* __restrict__ row_ptr,
                                                   const Edge* __restrict__ csr, const float* __restrict__ dinv,
                                                   const float* __restrict__ bias, const __bf16* __restrict__ Wlt,
                                                   const float* __restrict__ blin, float* __restrict__ out, int N) {
  __shared__ float hs[4][D];
  const int wid = threadIdx.x >> 6;
  const int lane = threadIdx.x & 63;
  int node = blockIdx.x * 4 + wid;
  if (node >= N) return;
  float dv = dinv[node];
  bf2 tv = *(const bf2*)(t + (size_t)node * D + lane * 2);
  float ax = dv * dv * (float)tv[0];
  float ay = dv * dv * (float)tv[1];
  int e = __builtin_amdgcn_readfirstlane(row_ptr[node]);
  int end = __builtin_amdgcn_readfirstlane(row_ptr[node + 1]);
  for (; e + 4 <= end; e += 4) {
    Edge e0 = csr[e], e1 = csr[e + 1], e2 = csr[e + 2], e3 = csr[e + 3];
    bf2 r0 = *(const bf2*)(t + (size_t)e0.s * D + lane * 2);
    bf2 r1 = *(const bf2*)(t + (size_t)e1.s * D + lane * 2);
    bf2 r2 = *(const bf2*)(t + (size_t)e2.s * D + lane * 2);
    bf2 r3 = *(const bf2*)(t + (size_t)e3.s * D + lane * 2);
    ax += e0.w * (float)r0[0]; ay += e0.w * (float)r0[1];
    ax += e1.w * (float)r1[0]; ay += e1.w * (float)r1[1];
    ax += e2.w * (float)r2[0]; ay += e2.w * (float)r2[1];
    ax += e3.w * (float)r3[0]; ay += e3.w * (float)r3[1];
  }
  for (; e < end; ++e) {
    Edge ed = csr[e];
    bf2 r = *(const bf2*)(t + (size_t)ed.s * D + lane * 2);
    ax += ed.w * (float)r[0]; ay += ed.w * (float)r[1];
  }
  float2 bv = *(const float2*)(bias + lane * 2);
  float2 hv;
  hv.x = tanhf(ax + bv.x);
  hv.y = tanhf(ay + bv.y);
  *(float2*)&hs[wid][lane * 2] = hv;  // intra-wave round trip; compiler inserts lgkmcnt wait

  // head: lanes 0..39 each compute one class; hs reads are wave-uniform (broadcast, conflict-free)
  if (lane < NCLS) {
    float acc = blin[lane];
    const __bf16* wp = Wlt + lane * D;
#pragma unroll
    for (int k8 = 0; k8 < D; k8 += 8) {
      bfrag w8 = *(const bfrag*)(wp + k8);
      float4 h0 = *(const float4*)&hs[wid][k8];
      float4 h1 = *(const float4*)&hs[wid][k8 + 4];
      acc += h0.x * (float)w8[0] + h0.y * (float)w8[1] + h0.z * (float)w8[2] + h0.w * (float)w8[3]
           + h1.x * (float)w8[4] + h1.y * (float)w8[5] + h1.z * (float)w8[6] + h1.w * (float)w8[7];
    }
    out[(size_t)node * NCLS + lane] = acc;
  }
}

// ---------------- MFMA GEMM: C[N,128] = A[N,128] @ B[128,128] ----------------
template <typename AT>
__global__ __launch_bounds__(256) void gemm_mfma(const AT* __restrict__ A, const __bf16* __restrict__ Wt,
                                                 __bf16* __restrict__ C, int N) {
  __shared__ __align__(16) __bf16 Bs[128][136];
  const int tid = threadIdx.x;
  const int wave = tid >> 6, lane = tid & 63;
  const int row0 = blockIdx.x * 128 + wave * 32;
  const int koff = (lane >> 4) * 8;

  for (int i = tid; i < 128 * 16; i += 256) {
    int n = i >> 4, seg = i & 15;
    *(uint4*)&Bs[n][seg * 8] = *(const uint4*)(Wt + n * D + seg * 8);
  }

  bfrag a[2][4];
#pragma unroll
  for (int mt = 0; mt < 2; ++mt) {
    int r = row0 + mt * 16 + (lane & 15);
    int rc = r < N ? r : N - 1;
    const AT* p = A + (size_t)rc * D;
#pragma unroll
    for (int kk = 0; kk < 4; ++kk) {
      if constexpr (sizeof(AT) == 4) {
        float4 u = *(const float4*)(p + kk * 32 + koff);
        float4 v = *(const float4*)(p + kk * 32 + koff + 4);
        bfrag f;
        f[0] = (__bf16)u.x; f[1] = (__bf16)u.y; f[2] = (__bf16)u.z; f[3] = (__bf16)u.w;
        f[4] = (__bf16)v.x; f[5] = (__bf16)v.y; f[6] = (__bf16)v.z; f[7] = (__bf16)v.w;
        a[mt][kk] = f;
      } else {
        a[mt][kk] = *(const bfrag*)(p + kk * 32 + koff);
      }
    }
  }
  __syncthreads();

  ffrag acc[2][8];
#pragma unroll
  for (int mt = 0; mt < 2; ++mt)
#pragma unroll
    for (int n = 0; n < 8; ++n) acc[mt][n] = (ffrag){0.f, 0.f, 0.f, 0.f};

#pragma unroll
  for (int kk = 0; kk < 4; ++kk) {
#pragma unroll
    for (int n = 0; n < 8; ++n) {
      bfrag b = *(const bfrag*)(&Bs[n * 16 + (lane & 15)][kk * 32 + koff]);
      acc[0][n] = __builtin_amdgcn_mfma_f32_16x16x32_bf16(a[0][kk], b, acc[0][n], 0, 0, 0);
      acc[1][n] = __builtin_amdgcn_mfma_f32_16x16x32_bf16(a[1][kk], b, acc[1][n], 0, 0, 0);
    }
  }

  int ocol = lane & 15;
#pragma unroll
  for (int mt = 0; mt < 2; ++mt) {
    int orow0 = row0 + mt * 16 + (lane >> 4) * 4;
#pragma unroll
    for (int n = 0; n < 8; ++n)
#pragma unroll
      for (int i = 0; i < 4; ++i) {
        int r = orow0 + i;
        if (r < N) C[(size_t)r * D + n * 16 + ocol] = (__bf16)acc[mt][n][i];
      }
  }
}

extern "C" void kernel_launch(void* const* d_in, const int* in_sizes, int n_in,
                              void* d_out, int out_size, void* d_ws, size_t ws_size,
                              hipStream_t stream) {
  const float* x    = (const float*)d_in[0];
  const int*   ei   = (const int*)d_in[1];
  const float* W1   = (const float*)d_in[2];
  const float* b1   = (const float*)d_in[3];
  const float* W2   = (const float*)d_in[4];
  const float* b2   = (const float*)d_in[5];
  const float* Wlin = (const float*)d_in[6];
  const float* blin = (const float*)d_in[7];
  float* out = (float*)d_out;

  const int N = in_sizes[0] / D;   // 50000
  const int E = in_sizes[1] / 2;   // 600000
  const int* srcp = ei;
  const int* dstp = ei + E;

  // workspace layout (~38 MB)
  char* ws = (char*)d_ws;
  float*  dinv   = (float*)(ws);                     // 200 KB
  int*    rowptr = (int*)(ws + (size_t)262144);      // N+1 ints
  int*    cursor = (int*)(ws + (size_t)524288);
  int*    bsum   = (int*)(ws + (size_t)786432);      // 196 ints
  __bf16* Wt1    = (__bf16*)(ws + (size_t)790528);   // 32 KB
  __bf16* Wt2    = (__bf16*)(ws + (size_t)823296);   // 32 KB
  __bf16* Wlt    = (__bf16*)(ws + (size_t)856064);   // 12.3 KB
  Edge*   csr    = (Edge*)(ws + (size_t)1048576);    // 4.8 MB
  __bf16* tb     = (__bf16*)(ws + (size_t)8388608);  // 12.8 MB
  __bf16* hb     = (__bf16*)(ws + (size_t)25165824); // 12.8 MB

  const int nb = (N + 255) / 256;  // 196
  dim3 b256(256);

  cvt_weights<<<152, b256, 0, stream>>>(W1, W2, Wlin, Wt1, Wt2, Wlt);

  // CSR build (proven R4 chain)
  hipMemsetAsync(cursor, 0, (size_t)N * sizeof(int), stream);
  deg_count_int<<<(E + 255) / 256, b256, 0, stream>>>(dstp, cursor, E);
  scan_block<<<nb, b256, 0, stream>>>(cursor, dinv, rowptr, bsum, N);
  scan_bsum<<<1, b256, 0, stream>>>(bsum, nb);
  scan_add<<<nb, b256, 0, stream>>>(rowptr, cursor, bsum, N, E);
  fill_csr<<<(E + 255) / 256, b256, 0, stream>>>(srcp, dstp, dinv, cursor, csr, E);

  const int gg = (N + 127) / 128;  // 391

  // layer 1 (A = fp32 x, converted in-register)
  gemm_mfma<float><<<gg, b256, 0, stream>>>(x, Wt1, tb, N);
  gather_bf16<<<(N + 3) / 4, b256, 0, stream>>>(tb, rowptr, csr, dinv, b1, hb, N);

  // layer 2
  gemm_mfma<__bf16><<<gg, b256, 0, stream>>>(hb, Wt2, tb, N);

  // layer-2 propagate + head fused
  gather_head<<<(N + 3) / 4, b256, 0, stream>>>(tb, rowptr, csr, dinv, b2, Wlt, blin, out, N);
}

// Round 8
// 238.624 us; speedup vs baseline: 1.1677x; 1.1677x over previous
//
#include <hip/hip_runtime.h>
#include <cmath>

#define D 128
#define NCLS 40

typedef __bf16 bfrag __attribute__((ext_vector_type(8)));
typedef __bf16 bf2 __attribute__((ext_vector_type(2)));
typedef float ffrag __attribute__((ext_vector_type(4)));
typedef unsigned int u32;

struct __align__(8) Edge { int s; float w; };

// ---------------- weights -> bf16, transposed [n][k] ----------------
__global__ __launch_bounds__(256) void cvt_weights(const float* __restrict__ W1, const float* __restrict__ W2,
                                                   const float* __restrict__ Wl, __bf16* __restrict__ Wt1,
                                                   __bf16* __restrict__ Wt2, __bf16* __restrict__ Wlt) {
  int i = blockIdx.x * 256 + threadIdx.x;
  if (i < 16384) {
    int n = i >> 7, k = i & 127;
    Wt1[i] = (__bf16)W1[k * D + n];
  } else if (i < 32768) {
    int j = i - 16384;
    int n = j >> 7, k = j & 127;
    Wt2[j] = (__bf16)W2[k * D + n];
  } else if (i < 32768 + 48 * D) {
    int j = i - 32768;
    int n = j >> 7, k = j & 127;
    Wlt[j] = (n < NCLS) ? (__bf16)Wl[k * NCLS + n] : (__bf16)0.0f;
  }
}

// ---------------- degree ----------------
__global__ __launch_bounds__(256) void deg_count_int(const int* __restrict__ dst, int* __restrict__ deg, int E) {
  int e = blockIdx.x * 256 + threadIdx.x;
  if (e < E) atomicAdd(&deg[dst[e]], 1);
}

// ---------------- hierarchical scan (3 kernels), dinv fused into pass 1 ----------------
__device__ inline int wave_incl_scan(int x, int lane) {
#pragma unroll
  for (int off = 1; off < 64; off <<= 1) {
    int y = __shfl_up(x, off, 64);
    if (lane >= off) x += y;
  }
  return x;
}

__global__ __launch_bounds__(256) void scan_block(const int* __restrict__ deg, float* __restrict__ dinv,
                                                  int* __restrict__ local, int* __restrict__ bsum, int n) {
  int i = blockIdx.x * 256 + threadIdx.x;
  int lane = threadIdx.x & 63, wid = threadIdx.x >> 6;
  int v = (i < n) ? deg[i] : 0;
  if (i < n) dinv[i] = rsqrtf((float)v + 1.0f);  // +1 = self-loop
  int x = wave_incl_scan(v, lane);
  __shared__ int ws4[4];
  if (lane == 63) ws4[wid] = x;
  __syncthreads();
  int wb = 0;
#pragma unroll
  for (int j = 0; j < 4; ++j) wb += (j < wid) ? ws4[j] : 0;
  if (i < n) local[i] = wb + x - v;
  if (threadIdx.x == 255) bsum[blockIdx.x] = wb + x;
}

__global__ __launch_bounds__(256) void scan_bsum(int* __restrict__ bsum, int nb) {
  int i = threadIdx.x;
  int lane = threadIdx.x & 63, wid = threadIdx.x >> 6;
  int v = (i < nb) ? bsum[i] : 0;
  int x = wave_incl_scan(v, lane);
  __shared__ int ws4[4];
  if (lane == 63) ws4[wid] = x;
  __syncthreads();
  int wb = 0;
#pragma unroll
  for (int j = 0; j < 4; ++j) wb += (j < wid) ? ws4[j] : 0;
  if (i < nb) bsum[i] = wb + x - v;
}

__global__ __launch_bounds__(256) void scan_add(int* __restrict__ rowptr, int* __restrict__ cursor,
                                                const int* __restrict__ bsum, int n, int E) {
  int i = blockIdx.x * 256 + threadIdx.x;
  if (i < n) {
    int r = rowptr[i] + bsum[blockIdx.x];
    rowptr[i] = r;
    cursor[i] = r;
  }
  if (i == 0) rowptr[n] = E;
}

// ---------------- CSR fill ----------------
__global__ __launch_bounds__(256) void fill_csr(const int* __restrict__ src, const int* __restrict__ dst,
                                                const float* __restrict__ dinv, int* __restrict__ cursor,
                                                Edge* __restrict__ csr, int E) {
  int e = blockIdx.x * 256 + threadIdx.x;
  if (e < E) {
    int s = src[e], d = dst[e];
    int pos = atomicAdd(&cursor[d], 1);
    Edge ed; ed.s = s; ed.w = dinv[s] * dinv[d];
    csr[pos] = ed;
  }
}

// ---------------- fused propagate with cooperative edge preload ----------------
// Phase 1: lanes 0..cnt-1 load the node's whole edge list in ONE instruction.
// Phase 2: broadcast (s,w) from lane j via readlane; row loads are the only
// memory latency and pipeline freely across unroll groups.
__global__ __launch_bounds__(256) void gather_bf16(const __bf16* __restrict__ t, const int* __restrict__ row_ptr,
                                                   const Edge* __restrict__ csr, const float* __restrict__ dinv,
                                                   const float* __restrict__ bias, __bf16* __restrict__ out, int N) {
  int node = blockIdx.x * 4 + (threadIdx.x >> 6);
  if (node >= N) return;
  int lane = threadIdx.x & 63;
  float dv = dinv[node];
  bf2 tv = *(const bf2*)(t + (size_t)node * D + lane * 2);
  float ax = dv * dv * (float)tv[0];
  float ay = dv * dv * (float)tv[1];
  int beg = __builtin_amdgcn_readfirstlane(row_ptr[node]);
  int end = __builtin_amdgcn_readfirstlane(row_ptr[node + 1]);
  int cnt = end - beg;
  int jmax = cnt <= 64 ? cnt : 64;
  // cooperative preload: all <=64 edges in flight with one 8B/lane load
  int es = 0; float ew = 0.0f;
  if (lane < jmax) {
    Edge ed = csr[beg + lane];
    es = ed.s; ew = ed.w;
  }
  int j = 0;
  for (; j + 4 <= jmax; j += 4) {
    int s0 = __shfl(es, j), s1 = __shfl(es, j + 1), s2 = __shfl(es, j + 2), s3 = __shfl(es, j + 3);
    float w0 = __shfl(ew, j), w1 = __shfl(ew, j + 1), w2 = __shfl(ew, j + 2), w3 = __shfl(ew, j + 3);
    bf2 r0 = *(const bf2*)(t + (size_t)s0 * D + lane * 2);
    bf2 r1 = *(const bf2*)(t + (size_t)s1 * D + lane * 2);
    bf2 r2 = *(const bf2*)(t + (size_t)s2 * D + lane * 2);
    bf2 r3 = *(const bf2*)(t + (size_t)s3 * D + lane * 2);
    ax += w0 * (float)r0[0]; ay += w0 * (float)r0[1];
    ax += w1 * (float)r1[0]; ay += w1 * (float)r1[1];
    ax += w2 * (float)r2[0]; ay += w2 * (float)r2[1];
    ax += w3 * (float)r3[0]; ay += w3 * (float)r3[1];
  }
  for (; j < jmax; ++j) {
    int s = __shfl(es, j);
    float w = __shfl(ew, j);
    bf2 r = *(const bf2*)(t + (size_t)s * D + lane * 2);
    ax += w * (float)r[0]; ay += w * (float)r[1];
  }
  for (; j < cnt; ++j) {  // degree > 64: effectively never for this graph
    Edge ed = csr[beg + j];
    bf2 r = *(const bf2*)(t + (size_t)ed.s * D + lane * 2);
    ax += ed.w * (float)r[0]; ay += ed.w * (float)r[1];
  }
  float2 bv = *(const float2*)(bias + lane * 2);
  bf2 o;
  o[0] = (__bf16)tanhf(ax + bv.x);
  o[1] = (__bf16)tanhf(ay + bv.y);
  __builtin_nontemporal_store(*(u32*)&o, (u32*)(out + (size_t)node * D + lane * 2));
}

// ---------------- MFMA GEMM: C[N,128] = A[N,128] @ B[128,128] ----------------
template <typename AT>
__global__ __launch_bounds__(256) void gemm_mfma(const AT* __restrict__ A, const __bf16* __restrict__ Wt,
                                                 __bf16* __restrict__ C, int N) {
  __shared__ __align__(16) __bf16 Bs[128][136];
  const int tid = threadIdx.x;
  const int wave = tid >> 6, lane = tid & 63;
  const int row0 = blockIdx.x * 128 + wave * 32;
  const int koff = (lane >> 4) * 8;

  for (int i = tid; i < 128 * 16; i += 256) {
    int n = i >> 4, seg = i & 15;
    *(uint4*)&Bs[n][seg * 8] = *(const uint4*)(Wt + n * D + seg * 8);
  }

  bfrag a[2][4];
#pragma unroll
  for (int mt = 0; mt < 2; ++mt) {
    int r = row0 + mt * 16 + (lane & 15);
    int rc = r < N ? r : N - 1;
    const AT* p = A + (size_t)rc * D;
#pragma unroll
    for (int kk = 0; kk < 4; ++kk) {
      if constexpr (sizeof(AT) == 4) {
        float4 u = *(const float4*)(p + kk * 32 + koff);
        float4 v = *(const float4*)(p + kk * 32 + koff + 4);
        bfrag f;
        f[0] = (__bf16)u.x; f[1] = (__bf16)u.y; f[2] = (__bf16)u.z; f[3] = (__bf16)u.w;
        f[4] = (__bf16)v.x; f[5] = (__bf16)v.y; f[6] = (__bf16)v.z; f[7] = (__bf16)v.w;
        a[mt][kk] = f;
      } else {
        a[mt][kk] = *(const bfrag*)(p + kk * 32 + koff);
      }
    }
  }
  __syncthreads();

  ffrag acc[2][8];
#pragma unroll
  for (int mt = 0; mt < 2; ++mt)
#pragma unroll
    for (int n = 0; n < 8; ++n) acc[mt][n] = (ffrag){0.f, 0.f, 0.f, 0.f};

#pragma unroll
  for (int kk = 0; kk < 4; ++kk) {
#pragma unroll
    for (int n = 0; n < 8; ++n) {
      bfrag b = *(const bfrag*)(&Bs[n * 16 + (lane & 15)][kk * 32 + koff]);
      acc[0][n] = __builtin_amdgcn_mfma_f32_16x16x32_bf16(a[0][kk], b, acc[0][n], 0, 0, 0);
      acc[1][n] = __builtin_amdgcn_mfma_f32_16x16x32_bf16(a[1][kk], b, acc[1][n], 0, 0, 0);
    }
  }

  int ocol = lane & 15;
#pragma unroll
  for (int mt = 0; mt < 2; ++mt) {
    int orow0 = row0 + mt * 16 + (lane >> 4) * 4;
#pragma unroll
    for (int n = 0; n < 8; ++n)
#pragma unroll
      for (int i = 0; i < 4; ++i) {
        int r = orow0 + i;
        if (r < N) C[(size_t)r * D + n * 16 + ocol] = (__bf16)acc[mt][n][i];
      }
  }
}

// ---------------- MFMA head: out[N,40] = H[N,128] @ Wlt^T + b ----------------
__global__ __launch_bounds__(256) void head_mfma(const __bf16* __restrict__ H, const __bf16* __restrict__ Wlt,
                                                 const float* __restrict__ bias, float* __restrict__ out, int N) {
  __shared__ __align__(16) __bf16 Ws[48][136];
  const int tid = threadIdx.x;
  const int wave = tid >> 6, lane = tid & 63;
  const int row0 = blockIdx.x * 128 + wave * 32;
  const int koff = (lane >> 4) * 8;

  for (int i = tid; i < 48 * 16; i += 256) {
    int n = i >> 4, seg = i & 15;
    *(uint4*)&Ws[n][seg * 8] = *(const uint4*)(Wlt + n * D + seg * 8);
  }

  bfrag a[2][4];
#pragma unroll
  for (int mt = 0; mt < 2; ++mt) {
    int r = row0 + mt * 16 + (lane & 15);
    int rc = r < N ? r : N - 1;
#pragma unroll
    for (int kk = 0; kk < 4; ++kk)
      a[mt][kk] = *(const bfrag*)(H + (size_t)rc * D + kk * 32 + koff);
  }
  __syncthreads();

  ffrag acc[2][3];
#pragma unroll
  for (int mt = 0; mt < 2; ++mt)
#pragma unroll
    for (int n = 0; n < 3; ++n) acc[mt][n] = (ffrag){0.f, 0.f, 0.f, 0.f};

#pragma unroll
  for (int kk = 0; kk < 4; ++kk) {
#pragma unroll
    for (int n = 0; n < 3; ++n) {
      bfrag b = *(const bfrag*)(&Ws[n * 16 + (lane & 15)][kk * 32 + koff]);
      acc[0][n] = __builtin_amdgcn_mfma_f32_16x16x32_bf16(a[0][kk], b, acc[0][n], 0, 0, 0);
      acc[1][n] = __builtin_amdgcn_mfma_f32_16x16x32_bf16(a[1][kk], b, acc[1][n], 0, 0, 0);
    }
  }

  int ocol = lane & 15;
#pragma unroll
  for (int mt = 0; mt < 2; ++mt) {
    int orow0 = row0 + mt * 16 + (lane >> 4) * 4;
#pragma unroll
    for (int n = 0; n < 3; ++n) {
      int c = n * 16 + ocol;
      if (c < NCLS) {
#pragma unroll
        for (int i = 0; i < 4; ++i) {
          int r = orow0 + i;
          if (r < N) out[(size_t)r * NCLS + c] = acc[mt][n][i] + bias[c];
        }
      }
    }
  }
}

extern "C" void kernel_launch(void* const* d_in, const int* in_sizes, int n_in,
                              void* d_out, int out_size, void* d_ws, size_t ws_size,
                              hipStream_t stream) {
  const float* x    = (const float*)d_in[0];
  const int*   ei   = (const int*)d_in[1];
  const float* W1   = (const float*)d_in[2];
  const float* b1   = (const float*)d_in[3];
  const float* W2   = (const float*)d_in[4];
  const float* b2   = (const float*)d_in[5];
  const float* Wlin = (const float*)d_in[6];
  const float* blin = (const float*)d_in[7];
  float* out = (float*)d_out;

  const int N = in_sizes[0] / D;   // 50000
  const int E = in_sizes[1] / 2;   // 600000
  const int* srcp = ei;
  const int* dstp = ei + E;

  // workspace layout (~38 MB)
  char* ws = (char*)d_ws;
  float*  dinv   = (float*)(ws);                     // 200 KB
  int*    rowptr = (int*)(ws + (size_t)262144);      // N+1 ints
  int*    cursor = (int*)(ws + (size_t)524288);
  int*    bsum   = (int*)(ws + (size_t)786432);      // 196 ints
  __bf16* Wt1    = (__bf16*)(ws + (size_t)790528);   // 32 KB
  __bf16* Wt2    = (__bf16*)(ws + (size_t)823296);   // 32 KB
  __bf16* Wlt    = (__bf16*)(ws + (size_t)856064);   // 12.3 KB
  Edge*   csr    = (Edge*)(ws + (size_t)1048576);    // 4.8 MB
  __bf16* tb     = (__bf16*)(ws + (size_t)8388608);  // 12.8 MB
  __bf16* hb     = (__bf16*)(ws + (size_t)25165824); // 12.8 MB

  const int nb = (N + 255) / 256;  // 196
  dim3 b256(256);

  cvt_weights<<<152, b256, 0, stream>>>(W1, W2, Wlin, Wt1, Wt2, Wlt);

  // CSR build (proven R4 chain)
  hipMemsetAsync(cursor, 0, (size_t)N * sizeof(int), stream);
  deg_count_int<<<(E + 255) / 256, b256, 0, stream>>>(dstp, cursor, E);
  scan_block<<<nb, b256, 0, stream>>>(cursor, dinv, rowptr, bsum, N);
  scan_bsum<<<1, b256, 0, stream>>>(bsum, nb);
  scan_add<<<nb, b256, 0, stream>>>(rowptr, cursor, bsum, N, E);
  fill_csr<<<(E + 255) / 256, b256, 0, stream>>>(srcp, dstp, dinv, cursor, csr, E);

  const int gg = (N + 127) / 128;  // 391

  // layer 1 (A = fp32 x, converted in-register)
  gemm_mfma<float><<<gg, b256, 0, stream>>>(x, Wt1, tb, N);
  gather_bf16<<<(N + 3) / 4, b256, 0, stream>>>(tb, rowptr, csr, dinv, b1, hb, N);

  // layer 2
  gemm_mfma<__bf16><<<gg, b256, 0, stream>>>(hb, Wt2, tb, N);
  gather_bf16<<<(N + 3) / 4, b256, 0, stream>>>(tb, rowptr, csr, dinv, b2, hb, N);

  // head
  head_mfma<<<gg, b256, 0, stream>>>(hb, Wlt, blin, out, N);
}

// Round 9
// 225.324 us; speedup vs baseline: 1.2366x; 1.0590x over previous
//
#include <hip/hip_runtime.h>
#include <cmath>

#define D 128
#define NCLS 40
#define GG 391           // gemm grid for N=50000, 128 rows/block
#define CVT_BLOCKS 152   // 38912 weight elems / 256

typedef __bf16 bfrag __attribute__((ext_vector_type(8)));
typedef __bf16 bf2 __attribute__((ext_vector_type(2)));
typedef float ffrag __attribute__((ext_vector_type(4)));
typedef unsigned int u32;

struct __align__(8) Edge { int s; float w; };

// ---------------- K1: weights -> bf16 transposed  ∥  zero(count) ----------------
__global__ __launch_bounds__(256) void init_kernel(const float* __restrict__ W1, const float* __restrict__ W2,
                                                   const float* __restrict__ Wl, __bf16* __restrict__ Wt1,
                                                   __bf16* __restrict__ Wt2, __bf16* __restrict__ Wlt,
                                                   int* __restrict__ count, int N) {
  int b = blockIdx.x;
  if (b < CVT_BLOCKS) {
    int i = b * 256 + threadIdx.x;
    if (i < 16384) {
      int n = i >> 7, k = i & 127;
      Wt1[i] = (__bf16)W1[k * D + n];
    } else if (i < 32768) {
      int j = i - 16384;
      int n = j >> 7, k = j & 127;
      Wt2[j] = (__bf16)W2[k * D + n];
    } else if (i < 32768 + 48 * D) {
      int j = i - 32768;
      int n = j >> 7, k = j & 127;
      Wlt[j] = (n < NCLS) ? (__bf16)Wl[k * NCLS + n] : (__bf16)0.0f;
    }
  } else {
    int i = (b - CVT_BLOCKS) * 256 + threadIdx.x;
    if (i < N) count[i] = 0;
  }
}

// ---------------- K2: gemm1 (fp32 A -> bf16 C)  ∥  deg_count ----------------
__global__ __launch_bounds__(256) void gemm1_deg(const float* __restrict__ A, const __bf16* __restrict__ Wt,
                                                 __bf16* __restrict__ C, int N,
                                                 const int* __restrict__ dst, int* __restrict__ count, int E) {
  __shared__ __align__(16) __bf16 Bs[128][136];
  if (blockIdx.x >= GG) {  // degree-count role
    int e = (blockIdx.x - GG) * 256 + threadIdx.x;
    if (e < E) atomicAdd(&count[dst[e]], 1);
    return;
  }
  const int tid = threadIdx.x;
  const int wave = tid >> 6, lane = tid & 63;
  const int row0 = blockIdx.x * 128 + wave * 32;
  const int koff = (lane >> 4) * 8;

  for (int i = tid; i < 128 * 16; i += 256) {
    int n = i >> 4, seg = i & 15;
    *(uint4*)&Bs[n][seg * 8] = *(const uint4*)(Wt + n * D + seg * 8);
  }

  bfrag a[2][4];
#pragma unroll
  for (int mt = 0; mt < 2; ++mt) {
    int r = row0 + mt * 16 + (lane & 15);
    int rc = r < N ? r : N - 1;
    const float* p = A + (size_t)rc * D;
#pragma unroll
    for (int kk = 0; kk < 4; ++kk) {
      float4 u = *(const float4*)(p + kk * 32 + koff);
      float4 v = *(const float4*)(p + kk * 32 + koff + 4);
      bfrag f;
      f[0] = (__bf16)u.x; f[1] = (__bf16)u.y; f[2] = (__bf16)u.z; f[3] = (__bf16)u.w;
      f[4] = (__bf16)v.x; f[5] = (__bf16)v.y; f[6] = (__bf16)v.z; f[7] = (__bf16)v.w;
      a[mt][kk] = f;
    }
  }
  __syncthreads();

  ffrag acc[2][8];
#pragma unroll
  for (int mt = 0; mt < 2; ++mt)
#pragma unroll
    for (int n = 0; n < 8; ++n) acc[mt][n] = (ffrag){0.f, 0.f, 0.f, 0.f};

#pragma unroll
  for (int kk = 0; kk < 4; ++kk) {
#pragma unroll
    for (int n = 0; n < 8; ++n) {
      bfrag b = *(const bfrag*)(&Bs[n * 16 + (lane & 15)][kk * 32 + koff]);
      acc[0][n] = __builtin_amdgcn_mfma_f32_16x16x32_bf16(a[0][kk], b, acc[0][n], 0, 0, 0);
      acc[1][n] = __builtin_amdgcn_mfma_f32_16x16x32_bf16(a[1][kk], b, acc[1][n], 0, 0, 0);
    }
  }

  int ocol = lane & 15;
#pragma unroll
  for (int mt = 0; mt < 2; ++mt) {
    int orow0 = row0 + mt * 16 + (lane >> 4) * 4;
#pragma unroll
    for (int n = 0; n < 8; ++n)
#pragma unroll
      for (int i = 0; i < 4; ++i) {
        int r = orow0 + i;
        if (r < N) C[(size_t)r * D + n * 16 + ocol] = (__bf16)acc[mt][n][i];
      }
  }
}

// ---------------- K3: per-block exclusive scan (dinv fused) ----------------
__device__ inline int wave_incl_scan(int x, int lane) {
#pragma unroll
  for (int off = 1; off < 64; off <<= 1) {
    int y = __shfl_up(x, off, 64);
    if (lane >= off) x += y;
  }
  return x;
}

__global__ __launch_bounds__(256) void scan_block(const int* __restrict__ deg, float* __restrict__ dinv,
                                                  int* __restrict__ local, int* __restrict__ bsum, int n) {
  int i = blockIdx.x * 256 + threadIdx.x;
  int lane = threadIdx.x & 63, wid = threadIdx.x >> 6;
  int v = (i < n) ? deg[i] : 0;
  if (i < n) dinv[i] = rsqrtf((float)v + 1.0f);  // +1 = self-loop
  int x = wave_incl_scan(v, lane);
  __shared__ int ws4[4];
  if (lane == 63) ws4[wid] = x;
  __syncthreads();
  int wb = 0;
#pragma unroll
  for (int j = 0; j < 4; ++j) wb += (j < wid) ? ws4[j] : 0;
  if (i < n) local[i] = wb + x - v;
  if (threadIdx.x == 255) bsum[blockIdx.x] = wb + x;
}

// ---------------- K4: add block prefix (self-computed from bsum) ----------------
__global__ __launch_bounds__(256) void scan_add2(int* __restrict__ rowptr, int* __restrict__ cursor,
                                                 const int* __restrict__ bsum, int n, int E, int nb) {
  const int tid = threadIdx.x;
  const int lane = tid & 63, wid = tid >> 6;
  // reduce bsum[0 .. blockIdx.x) across the block (nb <= 256)
  int v = (tid < nb && tid < (int)blockIdx.x) ? bsum[tid] : 0;
#pragma unroll
  for (int off = 32; off > 0; off >>= 1) v += __shfl_down(v, off, 64);
  __shared__ int ws4[4];
  __shared__ int offs;
  if (lane == 0) ws4[wid] = v;
  __syncthreads();
  if (tid == 0) offs = ws4[0] + ws4[1] + ws4[2] + ws4[3];
  __syncthreads();
  int i = blockIdx.x * 256 + tid;
  if (i < n) {
    int r = rowptr[i] + offs;
    rowptr[i] = r;
    cursor[i] = r;
  }
  if (i == 0) rowptr[n] = E;
}

// ---------------- K5: CSR fill ----------------
__global__ __launch_bounds__(256) void fill_csr(const int* __restrict__ src, const int* __restrict__ dst,
                                                const float* __restrict__ dinv, int* __restrict__ cursor,
                                                Edge* __restrict__ csr, int E) {
  int e = blockIdx.x * 256 + threadIdx.x;
  if (e < E) {
    int s = src[e], d = dst[e];
    int pos = atomicAdd(&cursor[d], 1);
    Edge ed; ed.s = s; ed.w = dinv[s] * dinv[d];
    csr[pos] = ed;
  }
}

// ---------------- gather: cooperative edge preload + row-load pipeline ----------------
__global__ __launch_bounds__(256) void gather_bf16(const __bf16* __restrict__ t, const int* __restrict__ row_ptr,
                                                   const Edge* __restrict__ csr, const float* __restrict__ dinv,
                                                   const float* __restrict__ bias, __bf16* __restrict__ out, int N) {
  int node = blockIdx.x * 4 + (threadIdx.x >> 6);
  if (node >= N) return;
  int lane = threadIdx.x & 63;
  float dv = dinv[node];
  bf2 tv = *(const bf2*)(t + (size_t)node * D + lane * 2);
  float ax = dv * dv * (float)tv[0];
  float ay = dv * dv * (float)tv[1];
  int beg = __builtin_amdgcn_readfirstlane(row_ptr[node]);
  int end = __builtin_amdgcn_readfirstlane(row_ptr[node + 1]);
  int cnt = end - beg;
  int jmax = cnt <= 64 ? cnt : 64;
  int es = 0; float ew = 0.0f;
  if (lane < jmax) {
    Edge ed = csr[beg + lane];
    es = ed.s; ew = ed.w;
  }
  int j = 0;
  for (; j + 4 <= jmax; j += 4) {
    int s0 = __shfl(es, j), s1 = __shfl(es, j + 1), s2 = __shfl(es, j + 2), s3 = __shfl(es, j + 3);
    float w0 = __shfl(ew, j), w1 = __shfl(ew, j + 1), w2 = __shfl(ew, j + 2), w3 = __shfl(ew, j + 3);
    bf2 r0 = *(const bf2*)(t + (size_t)s0 * D + lane * 2);
    bf2 r1 = *(const bf2*)(t + (size_t)s1 * D + lane * 2);
    bf2 r2 = *(const bf2*)(t + (size_t)s2 * D + lane * 2);
    bf2 r3 = *(const bf2*)(t + (size_t)s3 * D + lane * 2);
    ax += w0 * (float)r0[0]; ay += w0 * (float)r0[1];
    ax += w1 * (float)r1[0]; ay += w1 * (float)r1[1];
    ax += w2 * (float)r2[0]; ay += w2 * (float)r2[1];
    ax += w3 * (float)r3[0]; ay += w3 * (float)r3[1];
  }
  for (; j < jmax; ++j) {
    int s = __shfl(es, j);
    float w = __shfl(ew, j);
    bf2 r = *(const bf2*)(t + (size_t)s * D + lane * 2);
    ax += w * (float)r[0]; ay += w * (float)r[1];
  }
  for (; j < cnt; ++j) {  // degree > 64: effectively never
    Edge ed = csr[beg + j];
    bf2 r = *(const bf2*)(t + (size_t)ed.s * D + lane * 2);
    ax += ed.w * (float)r[0]; ay += ed.w * (float)r[1];
  }
  float2 bv = *(const float2*)(bias + lane * 2);
  bf2 o;
  o[0] = (__bf16)tanhf(ax + bv.x);
  o[1] = (__bf16)tanhf(ay + bv.y);
  __builtin_nontemporal_store(*(u32*)&o, (u32*)(out + (size_t)node * D + lane * 2));
}

// ---------------- MFMA GEMM (bf16 A) for layer 2 ----------------
__global__ __launch_bounds__(256) void gemm_mfma(const __bf16* __restrict__ A, const __bf16* __restrict__ Wt,
                                                 __bf16* __restrict__ C, int N) {
  __shared__ __align__(16) __bf16 Bs[128][136];
  const int tid = threadIdx.x;
  const int wave = tid >> 6, lane = tid & 63;
  const int row0 = blockIdx.x * 128 + wave * 32;
  const int koff = (lane >> 4) * 8;

  for (int i = tid; i < 128 * 16; i += 256) {
    int n = i >> 4, seg = i & 15;
    *(uint4*)&Bs[n][seg * 8] = *(const uint4*)(Wt + n * D + seg * 8);
  }

  bfrag a[2][4];
#pragma unroll
  for (int mt = 0; mt < 2; ++mt) {
    int r = row0 + mt * 16 + (lane & 15);
    int rc = r < N ? r : N - 1;
#pragma unroll
    for (int kk = 0; kk < 4; ++kk)
      a[mt][kk] = *(const bfrag*)(A + (size_t)rc * D + kk * 32 + koff);
  }
  __syncthreads();

  ffrag acc[2][8];
#pragma unroll
  for (int mt = 0; mt < 2; ++mt)
#pragma unroll
    for (int n = 0; n < 8; ++n) acc[mt][n] = (ffrag){0.f, 0.f, 0.f, 0.f};

#pragma unroll
  for (int kk = 0; kk < 4; ++kk) {
#pragma unroll
    for (int n = 0; n < 8; ++n) {
      bfrag b = *(const bfrag*)(&Bs[n * 16 + (lane & 15)][kk * 32 + koff]);
      acc[0][n] = __builtin_amdgcn_mfma_f32_16x16x32_bf16(a[0][kk], b, acc[0][n], 0, 0, 0);
      acc[1][n] = __builtin_amdgcn_mfma_f32_16x16x32_bf16(a[1][kk], b, acc[1][n], 0, 0, 0);
    }
  }

  int ocol = lane & 15;
#pragma unroll
  for (int mt = 0; mt < 2; ++mt) {
    int orow0 = row0 + mt * 16 + (lane >> 4) * 4;
#pragma unroll
    for (int n = 0; n < 8; ++n)
#pragma unroll
      for (int i = 0; i < 4; ++i) {
        int r = orow0 + i;
        if (r < N) C[(size_t)r * D + n * 16 + ocol] = (__bf16)acc[mt][n][i];
      }
  }
}

// ---------------- MFMA head ----------------
__global__ __launch_bounds__(256) void head_mfma(const __bf16* __restrict__ H, const __bf16* __restrict__ Wlt,
                                                 const float* __restrict__ bias, float* __restrict__ out, int N) {
  __shared__ __align__(16) __bf16 Ws[48][136];
  const int tid = threadIdx.x;
  const int wave = tid >> 6, lane = tid & 63;
  const int row0 = blockIdx.x * 128 + wave * 32;
  const int koff = (lane >> 4) * 8;

  for (int i = tid; i < 48 * 16; i += 256) {
    int n = i >> 4, seg = i & 15;
    *(uint4*)&Ws[n][seg * 8] = *(const uint4*)(Wlt + n * D + seg * 8);
  }

  bfrag a[2][4];
#pragma unroll
  for (int mt = 0; mt < 2; ++mt) {
    int r = row0 + mt * 16 + (lane & 15);
    int rc = r < N ? r : N - 1;
#pragma unroll
    for (int kk = 0; kk < 4; ++kk)
      a[mt][kk] = *(const bfrag*)(H + (size_t)rc * D + kk * 32 + koff);
  }
  __syncthreads();

  ffrag acc[2][3];
#pragma unroll
  for (int mt = 0; mt < 2; ++mt)
#pragma unroll
    for (int n = 0; n < 3; ++n) acc[mt][n] = (ffrag){0.f, 0.f, 0.f, 0.f};

#pragma unroll
  for (int kk = 0; kk < 4; ++kk) {
#pragma unroll
    for (int n = 0; n < 3; ++n) {
      bfrag b = *(const bfrag*)(&Ws[n * 16 + (lane & 15)][kk * 32 + koff]);
      acc[0][n] = __builtin_amdgcn_mfma_f32_16x16x32_bf16(a[0][kk], b, acc[0][n], 0, 0, 0);
      acc[1][n] = __builtin_amdgcn_mfma_f32_16x16x32_bf16(a[1][kk], b, acc[1][n], 0, 0, 0);
    }
  }

  int ocol = lane & 15;
#pragma unroll
  for (int mt = 0; mt < 2; ++mt) {
    int orow0 = row0 + mt * 16 + (lane >> 4) * 4;
#pragma unroll
    for (int n = 0; n < 3; ++n) {
      int c = n * 16 + ocol;
      if (c < NCLS) {
#pragma unroll
        for (int i = 0; i < 4; ++i) {
          int r = orow0 + i;
          if (r < N) out[(size_t)r * NCLS + c] = acc[mt][n][i] + bias[c];
        }
      }
    }
  }
}

extern "C" void kernel_launch(void* const* d_in, const int* in_sizes, int n_in,
                              void* d_out, int out_size, void* d_ws, size_t ws_size,
                              hipStream_t stream) {
  const float* x    = (const float*)d_in[0];
  const int*   ei   = (const int*)d_in[1];
  const float* W1   = (const float*)d_in[2];
  const float* b1   = (const float*)d_in[3];
  const float* W2   = (const float*)d_in[4];
  const float* b2   = (const float*)d_in[5];
  const float* Wlin = (const float*)d_in[6];
  const float* blin = (const float*)d_in[7];
  float* out = (float*)d_out;

  const int N = in_sizes[0] / D;   // 50000
  const int E = in_sizes[1] / 2;   // 600000
  const int* srcp = ei;
  const int* dstp = ei + E;

  // workspace layout (~38 MB)
  char* ws = (char*)d_ws;
  float*  dinv   = (float*)(ws);                     // 200 KB
  int*    rowptr = (int*)(ws + (size_t)262144);      // N+1 ints
  int*    cursor = (int*)(ws + (size_t)524288);      // doubles as deg/count
  int*    bsum   = (int*)(ws + (size_t)786432);      // 196 ints
  __bf16* Wt1    = (__bf16*)(ws + (size_t)790528);   // 32 KB
  __bf16* Wt2    = (__bf16*)(ws + (size_t)823296);   // 32 KB
  __bf16* Wlt    = (__bf16*)(ws + (size_t)856064);   // 12.3 KB
  Edge*   csr    = (Edge*)(ws + (size_t)1048576);    // 4.8 MB
  __bf16* tb     = (__bf16*)(ws + (size_t)8388608);  // 12.8 MB
  __bf16* hb     = (__bf16*)(ws + (size_t)25165824); // 12.8 MB

  const int nb = (N + 255) / 256;     // 196
  const int eb = (E + 255) / 256;     // 2344
  dim3 b256(256);

  // K1: weights + count init
  init_kernel<<<CVT_BLOCKS + nb, b256, 0, stream>>>(W1, W2, Wlin, Wt1, Wt2, Wlt, cursor, N);
  // K2: gemm1 (needs Wt1) ∥ deg_count (needs zeroed count)
  gemm1_deg<<<GG + eb, b256, 0, stream>>>(x, Wt1, tb, N, dstp, cursor, E);
  // K3-K5: scan + fill
  scan_block<<<nb, b256, 0, stream>>>(cursor, dinv, rowptr, bsum, N);
  scan_add2<<<nb, b256, 0, stream>>>(rowptr, cursor, bsum, N, E, nb);
  fill_csr<<<eb, b256, 0, stream>>>(srcp, dstp, dinv, cursor, csr, E);
  // layer 1 propagate
  gather_bf16<<<(N + 3) / 4, b256, 0, stream>>>(tb, rowptr, csr, dinv, b1, hb, N);
  // layer 2
  gemm_mfma<<<GG, b256, 0, stream>>>(hb, Wt2, tb, N);
  gather_bf16<<<(N + 3) / 4, b256, 0, stream>>>(tb, rowptr, csr, dinv, b2, hb, N);
  // head
  head_mfma<<<GG, b256, 0, stream>>>(hb, Wlt, blin, out, N);
}